// Round 2
// baseline (1002.930 us; speedup 1.0000x reference)
//
#include <hip/hip_runtime.h>
#include <stdint.h>

#define HW 65536
#define NB 16
#define NC 64
#define NT 1024
#define NWAVE 16

__device__ __forceinline__ uint32_t flip_f32(float f) {
  uint32_t u = __float_as_uint(f);
  return u ^ ((u & 0x80000000u) ? 0xFFFFFFFFu : 0x80000000u);
}

// One thread per 4 pixels: channel max + first argmax, write flipped key + payload.
__global__ __launch_bounds__(256) void pool_kernel(const float* __restrict__ x,
                                                   uint32_t* __restrict__ keys,
                                                   uint32_t* __restrict__ pay) {
  int gid = blockIdx.x * 256 + threadIdx.x;   // 0 .. NB*HW/4-1
  int b = gid >> 14;                          // 16384 quads per batch
  int q = gid & 16383;
  const float4* xb = (const float4*)(x + (size_t)b * NC * HW) + q;
  float4 best = xb[0];
  uint32_t cx = 0, cy = 0, cz = 0, cw = 0;
  for (int c = 1; c < NC; ++c) {
    float4 v = xb[(size_t)c * (HW / 4)];
    if (v.x > best.x) { best.x = v.x; cx = (uint32_t)c; }
    if (v.y > best.y) { best.y = v.y; cy = (uint32_t)c; }
    if (v.z > best.z) { best.z = v.z; cz = (uint32_t)c; }
    if (v.w > best.w) { best.w = v.w; cw = (uint32_t)c; }
  }
  uint32_t p = (uint32_t)q * 4u;
  uint4 ko, po;
  ko.x = flip_f32(best.x); po.x = (p + 0) | (cx << 16);
  ko.y = flip_f32(best.y); po.y = (p + 1) | (cy << 16);
  ko.z = flip_f32(best.z); po.z = (p + 2) | (cz << 16);
  ko.w = flip_f32(best.w); po.w = (p + 3) | (cw << 16);
  ((uint4*)keys)[gid] = ko;
  ((uint4*)pay)[gid] = po;
}

// One block per batch: 4-pass stable LSD radix sort (8-bit digits) + output emit.
__global__ __launch_bounds__(NT) void sort_kernel(uint32_t* __restrict__ keysA,
                                                  uint32_t* __restrict__ payA,
                                                  uint32_t* __restrict__ outbase) {
  __shared__ uint32_t wv[NWAVE * 256];
  __shared__ uint32_t hist[256];
  __shared__ uint32_t running[256];

  const int b = blockIdx.x;
  const int tid = threadIdx.x;
  const int wave = tid >> 6;
  const int lane = tid & 63;
  const uint64_t lmask_lt = (1ull << lane) - 1ull;

  // A buffers in ws; B buffers inside this block's OWN 1MB slice of d_out
  // (d_out per batch = 4*HW floats = 1MB; B needs 512KB of it). No cross-block overlap.
  uint32_t* bufK[2];
  uint32_t* bufP[2];
  bufK[0] = keysA + (size_t)b * HW;
  bufP[0] = payA + (size_t)b * HW;
  bufK[1] = outbase + (size_t)b * (4 * HW);
  bufP[1] = bufK[1] + HW;

  int cur = 0;
  for (int pass = 0; pass < 4; ++pass) {
    const int shift = pass * 8;
    uint32_t* kin = bufK[cur];
    uint32_t* pin = bufP[cur];
    uint32_t* kout = bufK[cur ^ 1];
    uint32_t* pout = bufP[cur ^ 1];

    // ---- histogram (per-wave, ballot-match leaders; no atomics) ----
    for (int j = tid; j < NWAVE * 256; j += NT) wv[j] = 0;
    __syncthreads();
    for (int s = 0; s < HW / NT; ++s) {
      uint32_t d = (kin[s * NT + tid] >> shift) & 255u;
      uint64_t mask = ~0ull;
      #pragma unroll
      for (int bit = 0; bit < 8; ++bit) {
        uint64_t bal = __ballot((d >> bit) & 1u);
        mask &= ((d >> bit) & 1u) ? bal : ~bal;
      }
      if ((mask & lmask_lt) == 0)   // leader of match group
        wv[wave * 256 + d] += (uint32_t)__popcll(mask);
    }
    __syncthreads();
    uint32_t mycnt = 0;
    if (tid < 256) {
      uint32_t tot = 0;
      #pragma unroll
      for (int w = 0; w < NWAVE; ++w) tot += wv[w * 256 + tid];
      mycnt = tot;
      hist[tid] = tot;
    }
    __syncthreads();
    // inclusive scan over 256 digits
    for (int off = 1; off < 256; off <<= 1) {
      uint32_t v = 0;
      if (tid < 256 && tid >= off) v = hist[tid - off];
      __syncthreads();
      if (tid < 256) hist[tid] += v;
      __syncthreads();
    }
    if (tid < 256) running[tid] = hist[tid] - mycnt;   // exclusive base
    __syncthreads();

    // ---- stable scatter, 64 slices of 1024 elements ----
    for (int s = 0; s < HW / NT; ++s) {
      for (int j = tid; j < NWAVE * 256; j += NT) wv[j] = 0;
      uint32_t k = kin[s * NT + tid];
      uint32_t pl = pin[s * NT + tid];
      uint32_t d = (k >> shift) & 255u;
      __syncthreads();
      uint64_t mask = ~0ull;
      #pragma unroll
      for (int bit = 0; bit < 8; ++bit) {
        uint64_t bal = __ballot((d >> bit) & 1u);
        mask &= ((d >> bit) & 1u) ? bal : ~bal;
      }
      uint32_t rw = (uint32_t)__popcll(mask & lmask_lt);
      if (rw == 0) wv[wave * 256 + d] = (uint32_t)__popcll(mask);
      __syncthreads();
      if (tid < 256) {
        uint32_t run = running[tid];
        #pragma unroll
        for (int w = 0; w < NWAVE; ++w) {
          uint32_t c = wv[w * 256 + tid];
          wv[w * 256 + tid] = run;   // exclusive offset for wave w, digit tid
          run += c;
        }
        running[tid] = run;
      }
      __syncthreads();
      uint32_t pos = wv[wave * 256 + d] + rw;
      kout[pos] = k;
      pout[pos] = pl;
      __syncthreads();
    }
    cur ^= 1;
  }

  // ---- emit output: [val, c*HW+p, row, col], coalesced float4 ----
  const uint32_t* kf = bufK[cur];   // cur==0 after 4 passes -> ws buffer (A)
  const uint32_t* pf = bufP[cur];
  float4* out = (float4*)outbase;
  for (int i = tid; i < HW; i += NT) {
    uint32_t u = kf[i];
    u ^= (u & 0x80000000u) ? 0x80000000u : 0xFFFFFFFFu;  // unflip
    uint32_t pl = pf[i];
    uint32_t p = pl & 65535u;
    uint32_t c = pl >> 16;
    float4 o;
    o.x = __uint_as_float(u);
    o.y = (float)(c * HW + p);
    o.z = (float)(p >> 8);
    o.w = (float)(p & 255u);
    out[(size_t)b * HW + i] = o;
  }
}

extern "C" void kernel_launch(void* const* d_in, const int* in_sizes, int n_in,
                              void* d_out, int out_size, void* d_ws, size_t ws_size,
                              hipStream_t stream) {
  const float* x = (const float*)d_in[0];
  uint32_t* keysA = (uint32_t*)d_ws;                 // 4 MB
  uint32_t* payA = keysA + (size_t)NB * HW;          // 4 MB
  pool_kernel<<<dim3(NB * HW / 4 / 256), dim3(256), 0, stream>>>(x, keysA, payA);
  sort_kernel<<<dim3(NB), dim3(NT), 0, stream>>>(keysA, payA, (uint32_t*)d_out);
}

// Round 3
// 506.510 us; speedup vs baseline: 1.9801x; 1.9801x over previous
//
#include <hip/hip_runtime.h>
#include <stdint.h>

#define HW 65536
#define NB 16
#define NC 64
#define BPB 64      // sort blocks per batch
#define EPB 1024    // elements per sort block
#define NTS 256     // threads per sort block (4 waves)
#define NWS 4
#define NDIG 256

__device__ __forceinline__ uint32_t flip_f32(float f) {
  uint32_t u = __float_as_uint(f);
  return u ^ ((u & 0x80000000u) ? 0xFFFFFFFFu : 0x80000000u);
}
__device__ __forceinline__ uint32_t unflip_u32(uint32_t u) {
  return u ^ ((u & 0x80000000u) ? 0x80000000u : 0xFFFFFFFFu);
}
// 64-lane match-any over an 8-bit digit: mask of lanes holding the same digit.
__device__ __forceinline__ uint64_t match_mask(uint32_t d) {
  uint64_t mask = ~0ull;
  #pragma unroll
  for (int bit = 0; bit < 8; ++bit) {
    uint64_t bal = __ballot((d >> bit) & 1u);
    mask &= ((d >> bit) & 1u) ? bal : ~bal;
  }
  return mask;
}

// ---- pool: channel max + first argmax, 4 pixels/thread, flipped key + packed payload ----
__global__ __launch_bounds__(256) void pool_kernel(const float* __restrict__ x,
                                                   uint32_t* __restrict__ keys,
                                                   uint32_t* __restrict__ pay) {
  int gid = blockIdx.x * 256 + threadIdx.x;   // 0 .. NB*HW/4-1
  int b = gid >> 14;
  int q = gid & 16383;
  const float4* xb = (const float4*)(x + (size_t)b * NC * HW) + q;
  float4 best = xb[0];
  uint32_t cx = 0, cy = 0, cz = 0, cw = 0;
  #pragma unroll 8
  for (int c = 1; c < NC; ++c) {
    float4 v = xb[(size_t)c * (HW / 4)];
    if (v.x > best.x) { best.x = v.x; cx = (uint32_t)c; }
    if (v.y > best.y) { best.y = v.y; cy = (uint32_t)c; }
    if (v.z > best.z) { best.z = v.z; cz = (uint32_t)c; }
    if (v.w > best.w) { best.w = v.w; cw = (uint32_t)c; }
  }
  uint32_t p = (uint32_t)q * 4u;
  uint4 ko, po;
  ko.x = flip_f32(best.x); po.x = (p + 0) | (cx << 16);
  ko.y = flip_f32(best.y); po.y = (p + 1) | (cy << 16);
  ko.z = flip_f32(best.z); po.z = (p + 2) | (cz << 16);
  ko.w = flip_f32(best.w); po.w = (p + 3) | (cw << 16);
  ((uint4*)keys)[gid] = ko;
  ((uint4*)pay)[gid] = po;
}

// ghist for batch b lives in d_out slack: ob + b*4HW + 2*HW, 16384 u32 (digit-major: [digit][block])
__device__ __forceinline__ uint32_t* gh_ptr(uint32_t* ob, int b) {
  return ob + ((size_t)b * 4 * HW) + 2 * HW;
}

// ---- per-block digit histogram ----
__global__ __launch_bounds__(NTS) void hist_kernel(const uint32_t* __restrict__ kbase,
                                                   size_t kstride,
                                                   uint32_t* __restrict__ ob, int shift) {
  __shared__ uint32_t wv[NWS * NDIG];
  const int bid = blockIdx.x, b = bid >> 6, blk = bid & 63;
  const int tid = threadIdx.x, wave = tid >> 6, lane = tid & 63;
  const uint64_t lt = (1ull << lane) - 1ull;
  #pragma unroll
  for (int j = 0; j < NWS; ++j) wv[j * NDIG + tid] = 0;
  __syncthreads();
  const uint32_t* kb = kbase + (size_t)b * kstride + (size_t)blk * EPB;
  for (int s = 0; s < EPB / NTS; ++s) {
    uint32_t d = (kb[s * NTS + tid] >> shift) & 255u;
    uint64_t m = match_mask(d);
    if ((m & lt) == 0) wv[wave * NDIG + d] += (uint32_t)__popcll(m);
  }
  __syncthreads();
  uint32_t tot = wv[tid] + wv[NDIG + tid] + wv[2 * NDIG + tid] + wv[3 * NDIG + tid];
  gh_ptr(ob, b)[(tid << 6) + blk] = tot;
}

// ---- exclusive scan of the 16384 (digit-major) counts, one block per batch ----
__global__ __launch_bounds__(1024) void scan_kernel(uint32_t* __restrict__ ob) {
  __shared__ uint32_t part[1024];
  const int b = blockIdx.x, tid = threadIdx.x;
  uint32_t* g = gh_ptr(ob, b);
  uint32_t loc[16];
  const uint4* g4 = (const uint4*)(g + tid * 16);
  #pragma unroll
  for (int i = 0; i < 4; ++i) {
    uint4 v = g4[i];
    loc[i * 4 + 0] = v.x; loc[i * 4 + 1] = v.y;
    loc[i * 4 + 2] = v.z; loc[i * 4 + 3] = v.w;
  }
  uint32_t sum = 0;
  #pragma unroll
  for (int i = 0; i < 16; ++i) sum += loc[i];
  part[tid] = sum;
  __syncthreads();
  for (int off = 1; off < 1024; off <<= 1) {
    uint32_t t = (tid >= off) ? part[tid - off] : 0u;
    __syncthreads();
    part[tid] += t;
    __syncthreads();
  }
  uint32_t run = tid ? part[tid - 1] : 0u;
  uint4* s4 = (uint4*)(g + tid * 16);
  #pragma unroll
  for (int i = 0; i < 4; ++i) {
    uint4 o;
    uint32_t c;
    c = loc[i * 4 + 0]; o.x = run; run += c;
    c = loc[i * 4 + 1]; o.y = run; run += c;
    c = loc[i * 4 + 2]; o.z = run; run += c;
    c = loc[i * 4 + 3]; o.w = run; run += c;
    s4[i] = o;
  }
}

// ---- stable scatter: global base (scanned hist) + local stable rank ----
__global__ __launch_bounds__(NTS) void scatter_kernel(const uint32_t* __restrict__ kbase,
                                                      const uint32_t* __restrict__ pbase,
                                                      size_t instride,
                                                      uint32_t* __restrict__ kobase,
                                                      uint32_t* __restrict__ pobase,
                                                      size_t outstride,
                                                      uint32_t* __restrict__ ob, int shift) {
  __shared__ uint32_t wv[NWS * NDIG];
  __shared__ uint32_t running[NDIG];
  const int bid = blockIdx.x, b = bid >> 6, blk = bid & 63;
  const int tid = threadIdx.x, wave = tid >> 6, lane = tid & 63;
  const uint64_t lt = (1ull << lane) - 1ull;
  running[tid] = gh_ptr(ob, b)[(tid << 6) + blk];
  const uint32_t* kb = kbase + (size_t)b * instride + (size_t)blk * EPB;
  const uint32_t* pb = pbase + (size_t)b * instride + (size_t)blk * EPB;
  uint32_t* ko = kobase + (size_t)b * outstride;
  uint32_t* po = pobase + (size_t)b * outstride;
  __syncthreads();
  for (int s = 0; s < EPB / NTS; ++s) {
    #pragma unroll
    for (int j = 0; j < NWS; ++j) wv[j * NDIG + tid] = 0;
    uint32_t k = kb[s * NTS + tid];
    uint32_t p = pb[s * NTS + tid];
    uint32_t d = (k >> shift) & 255u;
    __syncthreads();
    uint64_t m = match_mask(d);
    uint32_t rw = (uint32_t)__popcll(m & lt);
    if (rw == 0) wv[wave * NDIG + d] = (uint32_t)__popcll(m);
    __syncthreads();
    {
      uint32_t run = running[tid];
      #pragma unroll
      for (int w = 0; w < NWS; ++w) {
        uint32_t c = wv[w * NDIG + tid];
        wv[w * NDIG + tid] = run;
        run += c;
      }
      running[tid] = run;
    }
    __syncthreads();
    uint32_t pos = wv[wave * NDIG + d] + rw;
    ko[pos] = k;
    po[pos] = p;
    __syncthreads();
  }
}

// ---- emit [val, c*HW+p, row, col] from sorted A buffers ----
__global__ __launch_bounds__(256) void emit_kernel(const uint32_t* __restrict__ kf,
                                                   const uint32_t* __restrict__ pf,
                                                   float4* __restrict__ out) {
  int gid = blockIdx.x * 256 + threadIdx.x;   // 0 .. NB*HW/4-1
  uint4 k = ((const uint4*)kf)[gid];
  uint4 p = ((const uint4*)pf)[gid];
  float4 o[4];
  uint32_t ks[4] = {k.x, k.y, k.z, k.w};
  uint32_t ps[4] = {p.x, p.y, p.z, p.w};
  #pragma unroll
  for (int j = 0; j < 4; ++j) {
    uint32_t u = unflip_u32(ks[j]);
    uint32_t pl = ps[j];
    uint32_t pp = pl & 65535u;
    uint32_t c = pl >> 16;
    o[j].x = __uint_as_float(u);
    o[j].y = (float)(c * HW + pp);
    o[j].z = (float)(pp >> 8);
    o[j].w = (float)(pp & 255u);
  }
  #pragma unroll
  for (int j = 0; j < 4; ++j) out[(size_t)gid * 4 + j] = o[j];
}

extern "C" void kernel_launch(void* const* d_in, const int* in_sizes, int n_in,
                              void* d_out, int out_size, void* d_ws, size_t ws_size,
                              hipStream_t stream) {
  const float* x = (const float*)d_in[0];
  uint32_t* keysA = (uint32_t*)d_ws;               // 4 MB
  uint32_t* payA = keysA + (size_t)NB * HW;        // 4 MB
  uint32_t* ob = (uint32_t*)d_out;                 // B keys/pay + ghist live in d_out slack

  pool_kernel<<<dim3(NB * HW / 4 / 256), dim3(256), 0, stream>>>(x, keysA, payA);

  const int nblk = NB * BPB;   // 1024
  for (int p = 0; p < 4; ++p) {
    int shift = p * 8;
    bool even = ((p & 1) == 0);
    const uint32_t* kin = even ? keysA : ob;
    const uint32_t* pin = even ? payA : ob + HW;
    size_t sin = even ? (size_t)HW : (size_t)4 * HW;
    uint32_t* kout = even ? ob : keysA;
    uint32_t* pout = even ? ob + HW : payA;
    size_t sout = even ? (size_t)4 * HW : (size_t)HW;
    hist_kernel<<<dim3(nblk), dim3(NTS), 0, stream>>>(kin, sin, ob, shift);
    scan_kernel<<<dim3(NB), dim3(1024), 0, stream>>>(ob);
    scatter_kernel<<<dim3(nblk), dim3(NTS), 0, stream>>>(kin, pin, sin, kout, pout, sout, ob, shift);
  }
  // after 4 passes sorted data is back in A; emit overwrites d_out
  emit_kernel<<<dim3(NB * HW / 4 / 256), dim3(256), 0, stream>>>(keysA, payA, (float4*)d_out);
}

// Round 4
// 496.172 us; speedup vs baseline: 2.0213x; 1.0208x over previous
//
#include <hip/hip_runtime.h>
#include <stdint.h>

#define HW 65536
#define NB 16
#define NC 64
#define BPB 64      // sort blocks per batch
#define EPB 1024    // elements per sort block
#define NTS 256     // threads per sort block (4 waves)
#define NWS 4
#define NDIG 256

__device__ __forceinline__ uint32_t flip_f32(float f) {
  uint32_t u = __float_as_uint(f);
  return u ^ ((u & 0x80000000u) ? 0xFFFFFFFFu : 0x80000000u);
}
__device__ __forceinline__ uint32_t unflip_u32(uint32_t u) {
  return u ^ ((u & 0x80000000u) ? 0x80000000u : 0xFFFFFFFFu);
}
// pack (key, channel) so that u64-max == (max key, then min channel) — branchless,
// iteration-order-independent first-argmax.
__device__ __forceinline__ uint64_t pack_kc(float f, int c) {
  return (((uint64_t)flip_f32(f)) << 6) | (uint64_t)(63 - c);
}
// 64-lane match-any over an 8-bit digit: mask of lanes holding the same digit.
__device__ __forceinline__ uint64_t match_mask(uint32_t d) {
  uint64_t mask = ~0ull;
  #pragma unroll
  for (int bit = 0; bit < 8; ++bit) {
    uint64_t bal = __ballot((d >> bit) & 1u);
    mask &= ((d >> bit) & 1u) ? bal : ~bal;
  }
  return mask;
}

// ---- pool: channel max + first argmax, 4 pixels/thread, branchless packed max ----
__global__ __launch_bounds__(256) void pool_kernel(const float* __restrict__ x,
                                                   uint32_t* __restrict__ keys,
                                                   uint32_t* __restrict__ pay) {
  int gid = blockIdx.x * 256 + threadIdx.x;   // 0 .. NB*HW/4-1
  int b = gid >> 14;
  int q = gid & 16383;
  const float4* xb = (const float4*)(x + (size_t)b * NC * HW) + q;
  float4 v0 = xb[0];
  uint64_t b0 = pack_kc(v0.x, 0);
  uint64_t b1 = pack_kc(v0.y, 0);
  uint64_t b2 = pack_kc(v0.z, 0);
  uint64_t b3 = pack_kc(v0.w, 0);
  #pragma unroll 16
  for (int c = 1; c < NC; ++c) {
    float4 v = xb[(size_t)c * (HW / 4)];
    uint64_t p0 = pack_kc(v.x, c); b0 = (p0 > b0) ? p0 : b0;
    uint64_t p1 = pack_kc(v.y, c); b1 = (p1 > b1) ? p1 : b1;
    uint64_t p2 = pack_kc(v.z, c); b2 = (p2 > b2) ? p2 : b2;
    uint64_t p3 = pack_kc(v.w, c); b3 = (p3 > b3) ? p3 : b3;
  }
  uint32_t p = (uint32_t)q * 4u;
  uint4 ko, po;
  ko.x = (uint32_t)(b0 >> 6); po.x = (p + 0) | ((63u - (uint32_t)(b0 & 63u)) << 16);
  ko.y = (uint32_t)(b1 >> 6); po.y = (p + 1) | ((63u - (uint32_t)(b1 & 63u)) << 16);
  ko.z = (uint32_t)(b2 >> 6); po.z = (p + 2) | ((63u - (uint32_t)(b2 & 63u)) << 16);
  ko.w = (uint32_t)(b3 >> 6); po.w = (p + 3) | ((63u - (uint32_t)(b3 & 63u)) << 16);
  ((uint4*)keys)[gid] = ko;
  ((uint4*)pay)[gid] = po;
}

// ghist for batch b lives in d_out slack: ob + b*4HW + 2*HW, 16384 u32 (digit-major: [digit][block])
__device__ __forceinline__ uint32_t* gh_ptr(uint32_t* ob, int b) {
  return ob + ((size_t)b * 4 * HW) + 2 * HW;
}

// ---- per-block digit histogram ----
__global__ __launch_bounds__(NTS) void hist_kernel(const uint32_t* __restrict__ kbase,
                                                   size_t kstride,
                                                   uint32_t* __restrict__ ob, int shift) {
  __shared__ uint32_t wv[NWS * NDIG];
  const int bid = blockIdx.x, b = bid >> 6, blk = bid & 63;
  const int tid = threadIdx.x, wave = tid >> 6, lane = tid & 63;
  const uint64_t lt = (1ull << lane) - 1ull;
  #pragma unroll
  for (int j = 0; j < NWS; ++j) wv[j * NDIG + tid] = 0;
  __syncthreads();
  const uint32_t* kb = kbase + (size_t)b * kstride + (size_t)blk * EPB;
  for (int s = 0; s < EPB / NTS; ++s) {
    uint32_t d = (kb[s * NTS + tid] >> shift) & 255u;
    uint64_t m = match_mask(d);
    if ((m & lt) == 0) wv[wave * NDIG + d] += (uint32_t)__popcll(m);
  }
  __syncthreads();
  uint32_t tot = wv[tid] + wv[NDIG + tid] + wv[2 * NDIG + tid] + wv[3 * NDIG + tid];
  gh_ptr(ob, b)[(tid << 6) + blk] = tot;
}

// ---- exclusive scan of the 16384 (digit-major) counts, one block per batch ----
__global__ __launch_bounds__(1024) void scan_kernel(uint32_t* __restrict__ ob) {
  __shared__ uint32_t part[1024];
  const int b = blockIdx.x, tid = threadIdx.x;
  uint32_t* g = gh_ptr(ob, b);
  uint32_t loc[16];
  const uint4* g4 = (const uint4*)(g + tid * 16);
  #pragma unroll
  for (int i = 0; i < 4; ++i) {
    uint4 v = g4[i];
    loc[i * 4 + 0] = v.x; loc[i * 4 + 1] = v.y;
    loc[i * 4 + 2] = v.z; loc[i * 4 + 3] = v.w;
  }
  uint32_t sum = 0;
  #pragma unroll
  for (int i = 0; i < 16; ++i) sum += loc[i];
  part[tid] = sum;
  __syncthreads();
  for (int off = 1; off < 1024; off <<= 1) {
    uint32_t t = (tid >= off) ? part[tid - off] : 0u;
    __syncthreads();
    part[tid] += t;
    __syncthreads();
  }
  uint32_t run = tid ? part[tid - 1] : 0u;
  uint4* s4 = (uint4*)(g + tid * 16);
  #pragma unroll
  for (int i = 0; i < 4; ++i) {
    uint4 o;
    uint32_t c;
    c = loc[i * 4 + 0]; o.x = run; run += c;
    c = loc[i * 4 + 1]; o.y = run; run += c;
    c = loc[i * 4 + 2]; o.z = run; run += c;
    c = loc[i * 4 + 3]; o.w = run; run += c;
    s4[i] = o;
  }
}

// ---- stable scatter: global base (scanned hist) + local stable rank ----
__global__ __launch_bounds__(NTS) void scatter_kernel(const uint32_t* __restrict__ kbase,
                                                      const uint32_t* __restrict__ pbase,
                                                      size_t instride,
                                                      uint32_t* __restrict__ kobase,
                                                      uint32_t* __restrict__ pobase,
                                                      size_t outstride,
                                                      uint32_t* __restrict__ ob, int shift) {
  __shared__ uint32_t wv[NWS * NDIG];
  __shared__ uint32_t running[NDIG];
  const int bid = blockIdx.x, b = bid >> 6, blk = bid & 63;
  const int tid = threadIdx.x, wave = tid >> 6, lane = tid & 63;
  const uint64_t lt = (1ull << lane) - 1ull;
  running[tid] = gh_ptr(ob, b)[(tid << 6) + blk];
  const uint32_t* kb = kbase + (size_t)b * instride + (size_t)blk * EPB;
  const uint32_t* pb = pbase + (size_t)b * instride + (size_t)blk * EPB;
  uint32_t* ko = kobase + (size_t)b * outstride;
  uint32_t* po = pobase + (size_t)b * outstride;
  __syncthreads();
  for (int s = 0; s < EPB / NTS; ++s) {
    #pragma unroll
    for (int j = 0; j < NWS; ++j) wv[j * NDIG + tid] = 0;
    uint32_t k = kb[s * NTS + tid];
    uint32_t p = pb[s * NTS + tid];
    uint32_t d = (k >> shift) & 255u;
    __syncthreads();
    uint64_t m = match_mask(d);
    uint32_t rw = (uint32_t)__popcll(m & lt);
    if (rw == 0) wv[wave * NDIG + d] = (uint32_t)__popcll(m);
    __syncthreads();
    {
      uint32_t run = running[tid];
      #pragma unroll
      for (int w = 0; w < NWS; ++w) {
        uint32_t c = wv[w * NDIG + tid];
        wv[w * NDIG + tid] = run;
        run += c;
      }
      running[tid] = run;
    }
    __syncthreads();
    uint32_t pos = wv[wave * NDIG + d] + rw;
    ko[pos] = k;
    po[pos] = p;
    __syncthreads();
  }
}

// ---- emit [val, c*HW+p, row, col] from sorted A buffers ----
__global__ __launch_bounds__(256) void emit_kernel(const uint32_t* __restrict__ kf,
                                                   const uint32_t* __restrict__ pf,
                                                   float4* __restrict__ out) {
  int gid = blockIdx.x * 256 + threadIdx.x;   // 0 .. NB*HW/4-1
  uint4 k = ((const uint4*)kf)[gid];
  uint4 p = ((const uint4*)pf)[gid];
  float4 o[4];
  uint32_t ks[4] = {k.x, k.y, k.z, k.w};
  uint32_t ps[4] = {p.x, p.y, p.z, p.w};
  #pragma unroll
  for (int j = 0; j < 4; ++j) {
    uint32_t u = unflip_u32(ks[j]);
    uint32_t pl = ps[j];
    uint32_t pp = pl & 65535u;
    uint32_t c = pl >> 16;
    o[j].x = __uint_as_float(u);
    o[j].y = (float)(c * HW + pp);
    o[j].z = (float)(pp >> 8);
    o[j].w = (float)(pp & 255u);
  }
  #pragma unroll
  for (int j = 0; j < 4; ++j) out[(size_t)gid * 4 + j] = o[j];
}

extern "C" void kernel_launch(void* const* d_in, const int* in_sizes, int n_in,
                              void* d_out, int out_size, void* d_ws, size_t ws_size,
                              hipStream_t stream) {
  const float* x = (const float*)d_in[0];
  uint32_t* keysA = (uint32_t*)d_ws;               // 4 MB
  uint32_t* payA = keysA + (size_t)NB * HW;        // 4 MB
  uint32_t* ob = (uint32_t*)d_out;                 // B keys/pay + ghist live in d_out slack

  pool_kernel<<<dim3(NB * HW / 4 / 256), dim3(256), 0, stream>>>(x, keysA, payA);

  const int nblk = NB * BPB;   // 1024
  for (int p = 0; p < 4; ++p) {
    int shift = p * 8;
    bool even = ((p & 1) == 0);
    const uint32_t* kin = even ? keysA : ob;
    const uint32_t* pin = even ? payA : ob + HW;
    size_t sin = even ? (size_t)HW : (size_t)4 * HW;
    uint32_t* kout = even ? ob : keysA;
    uint32_t* pout = even ? ob + HW : payA;
    size_t sout = even ? (size_t)4 * HW : (size_t)HW;
    hist_kernel<<<dim3(nblk), dim3(NTS), 0, stream>>>(kin, sin, ob, shift);
    scan_kernel<<<dim3(NB), dim3(1024), 0, stream>>>(ob);
    scatter_kernel<<<dim3(nblk), dim3(NTS), 0, stream>>>(kin, pin, sin, kout, pout, sout, ob, shift);
  }
  // after 4 passes sorted data is back in A; emit overwrites d_out
  emit_kernel<<<dim3(NB * HW / 4 / 256), dim3(256), 0, stream>>>(keysA, payA, (float4*)d_out);
}